// Round 1
// baseline (27811.032 us; speedup 1.0000x reference)
//
#include <hip/hip_runtime.h>
#include <hip/hip_bf16.h>

// CharLSTM: B=128, TW=256, TC=25, V=128, D=32, H=64 (4H=256)
// N = B*TW = 32768 independent sequences of length 25.
//
// Decomposition: 256-thread block; thread j owns gate-column j:
//   W[:,j] (32 regs), U[:,j] (64 regs), b[j]. Block processes S=8
//   sequences; h broadcast via LDS (same-address ds_read_b128),
//   gate values exchanged via LDS abuf, c replicated in registers
//   across the 4 waves (updates are wave-uniform).

#define S_SEQ 8
#define TC_LEN 25
#define H_N 64
#define D_N 32
#define G4_N 256

__device__ __forceinline__ float sigmoid_f(float x) {
    return __fdividef(1.0f, 1.0f + __expf(-x));
}
__device__ __forceinline__ float tanh_f(float x) {
    // tanh(x) = 1 - 2/(exp(2x)+1); exact at saturation, ~1e-7 rel error.
    return 1.0f - __fdividef(2.0f, __expf(2.0f * x) + 1.0f);
}

__global__ __launch_bounds__(256, 2) void char_lstm_kernel(
    const int* __restrict__ chars,   // [N][25]
    const float* __restrict__ E,     // [128][32]
    const float* __restrict__ W,     // [32][256]
    const float* __restrict__ U,     // [64][256]
    const float* __restrict__ b,     // [256]
    float* __restrict__ out)         // [N][64]
{
    const int j = threadIdx.x;            // 0..255 = gate column
    const int seq0 = blockIdx.x * S_SEQ;

    __shared__ __align__(16) float xbuf[S_SEQ][D_N];   // x_t per sequence
    __shared__ __align__(16) float hbuf[S_SEQ][H_N];   // h_t per sequence
    __shared__ __align__(16) float abuf[S_SEQ][G4_N];  // activated gates

    // ---- weights for column j into registers (coalesced, L2-hot) ----
    float Wreg[D_N];
#pragma unroll
    for (int d = 0; d < D_N; ++d) Wreg[d] = W[d * G4_N + j];
    float Ureg[H_N];
#pragma unroll
    for (int k = 0; k < H_N; ++k) Ureg[k] = U[k * G4_N + j];
    const float breg = b[j];

    // ---- zero initial h in LDS; c in registers (replicated per wave) ----
    for (int r = j; r < S_SEQ * H_N; r += 256) (&hbuf[0][0])[r] = 0.0f;

    float c[S_SEQ];
#pragma unroll
    for (int s = 0; s < S_SEQ; ++s) c[s] = 0.0f;

    const int sg = j >> 5;        // gather: sequence 0..7
    const int dg = j & 31;        // gather: embed dim 0..31
    const int gate = j >> 6;      // 0:i 1:f 2:g 3:o (wave-uniform)
    const int u = j & 63;         // unit index

    for (int t = 0; t < TC_LEN; ++t) {
        // ---- gather x_t = E[chars[s][t]] for all 8 sequences ----
        {
            const int ch = chars[(seq0 + sg) * TC_LEN + t];
            xbuf[sg][dg] = E[ch * D_N + dg];
        }
        __syncthreads();   // A: xbuf + hbuf(prev) visible

        // ---- z[j] = b + x.W[:,j] + h.U[:,j]  (per sequence) ----
        float acc[S_SEQ];
#pragma unroll
        for (int s = 0; s < S_SEQ; ++s) acc[s] = breg;

#pragma unroll
        for (int d4 = 0; d4 < D_N / 4; ++d4) {
#pragma unroll
            for (int s = 0; s < S_SEQ; ++s) {
                const float4 xv = *reinterpret_cast<const float4*>(&xbuf[s][d4 * 4]);
                acc[s] += xv.x * Wreg[d4 * 4 + 0];
                acc[s] += xv.y * Wreg[d4 * 4 + 1];
                acc[s] += xv.z * Wreg[d4 * 4 + 2];
                acc[s] += xv.w * Wreg[d4 * 4 + 3];
            }
        }
#pragma unroll
        for (int k4 = 0; k4 < H_N / 4; ++k4) {
#pragma unroll
            for (int s = 0; s < S_SEQ; ++s) {
                const float4 hv = *reinterpret_cast<const float4*>(&hbuf[s][k4 * 4]);
                acc[s] += hv.x * Ureg[k4 * 4 + 0];
                acc[s] += hv.y * Ureg[k4 * 4 + 1];
                acc[s] += hv.z * Ureg[k4 * 4 + 2];
                acc[s] += hv.w * Ureg[k4 * 4 + 3];
            }
        }

        // ---- nonlinearity (wave-uniform gate) + exchange via LDS ----
#pragma unroll
        for (int s = 0; s < S_SEQ; ++s) {
            const float z = acc[s];
            const float av = (gate == 2) ? tanh_f(z) : sigmoid_f(z);
            abuf[s][j] = av;
        }
        __syncthreads();   // B: abuf visible; z-loop reads of xbuf/hbuf done

        // ---- cell update, replicated across waves; wave 0 writes h ----
#pragma unroll
        for (int s = 0; s < S_SEQ; ++s) {
            const float iv = abuf[s][u];
            const float fv = abuf[s][u + 64];
            const float gv = abuf[s][u + 128];
            const float ov = abuf[s][u + 192];
            c[s] = fv * c[s] + iv * gv;
            const float hv = ov * tanh_f(c[s]);
            if (j < H_N) hbuf[s][u] = hv;
        }
    }
    __syncthreads();

    // ---- write h_last: out[(seq0+s)*64 + u], coalesced ----
#pragma unroll
    for (int rep = 0; rep < S_SEQ / 4; ++rep) {
        const int s = (j >> 6) + rep * 4;
        out[(seq0 + s) * H_N + (j & 63)] = hbuf[s][j & 63];
    }
}

extern "C" void kernel_launch(void* const* d_in, const int* in_sizes, int n_in,
                              void* d_out, int out_size, void* d_ws, size_t ws_size,
                              hipStream_t stream) {
    const int*   chars = (const int*)d_in[0];
    const float* E     = (const float*)d_in[1];
    const float* W     = (const float*)d_in[2];
    const float* U     = (const float*)d_in[3];
    const float* b     = (const float*)d_in[4];
    float* out = (float*)d_out;

    const int N = in_sizes[0] / TC_LEN;          // 32768 sequences
    const int blocks = (N + S_SEQ - 1) / S_SEQ;  // 4096

    char_lstm_kernel<<<blocks, 256, 0, stream>>>(chars, E, W, U, b, out);
}

// Round 2
// 11964.625 us; speedup vs baseline: 2.3244x; 2.3244x over previous
//
#include <hip/hip_runtime.h>
#include <hip/hip_bf16.h>

// CharLSTM: B=128, TW=256, TC=25, V=128, D=32, H=64 (4H=256)
// N = 32768 independent length-25 sequences.
//
// R2 design:
//  - Prologue kernel computes EWb[v][j] = sum_d E[v][d]*W[d][j] + b[j]
//    (128x256 fp32 = 131 KB in d_ws, L2-resident). Removes the x-matmul
//    (1/3 of FLOPs) and the 32-reg W column -> no spills.
//  - Main kernel: 256 threads = gate-column j; block owns 8 sequences.
//    Thread regs: Ureg[64] (U column j), acc[8], ew[8], c for 2 seqs.
//    h broadcast via LDS float4 reads; gates exchanged via LDS abuf;
//    wave w performs the c/h update for sequences {2w, 2w+1} only.

#define S_SEQ 8
#define TC_LEN 25
#define H_N 64
#define D_N 32
#define G4_N 256
#define V_N 128

__device__ __forceinline__ float sigmoid_f(float x) {
    return __fdividef(1.0f, 1.0f + __expf(-x));
}
__device__ __forceinline__ float tanh_f(float x) {
    // tanh(x) = 1 - 2/(exp(2x)+1); exact at saturation, ~1e-7 rel error.
    return 1.0f - __fdividef(2.0f, __expf(2.0f * x) + 1.0f);
}

// ---- prologue: EWb = E*W + b  (128 vocab rows x 256 gate cols) ----
__global__ void ew_precompute(const float* __restrict__ E,
                              const float* __restrict__ W,
                              const float* __restrict__ b,
                              float* __restrict__ EWb) {
    const int v = blockIdx.x;    // vocab row
    const int j = threadIdx.x;   // gate column
    float acc = b[j];
#pragma unroll
    for (int d = 0; d < D_N; ++d)
        acc = fmaf(E[v * D_N + d], W[d * G4_N + j], acc);
    EWb[v * G4_N + j] = acc;
}

__global__ __launch_bounds__(256, 2) void char_lstm_kernel(
    const int* __restrict__ chars,   // [N][25]
    const float* __restrict__ U,     // [64][256]
    const float* __restrict__ EWb,   // [128][256]
    float* __restrict__ out)         // [N][64]
{
    const int j = threadIdx.x;            // gate column 0..255
    const int seq0 = blockIdx.x * S_SEQ;

    __shared__ __align__(16) float hbuf[S_SEQ][H_N];     // 2 KB
    __shared__ __align__(16) float abuf[S_SEQ][G4_N];    // 8 KB
    __shared__ int ibuf[S_SEQ * TC_LEN];                 // 800 B

    // U column j into registers (coalesced, L2-hot: 64 KB table)
    float Ureg[H_N];
#pragma unroll
    for (int k = 0; k < H_N; ++k) Ureg[k] = U[k * G4_N + j];

    // stage this block's chars (200 consecutive ints, coalesced)
    if (j < S_SEQ * TC_LEN) ibuf[j] = chars[seq0 * TC_LEN + j];

    // zero initial h
    for (int r = j; r < S_SEQ * H_N; r += 256) (&hbuf[0][0])[r] = 0.0f;

    const int wave = j >> 6;                 // 0..3 == gate (i,f,g,o), wave-uniform
    const int u = j & 63;                    // unit index
    const int sA = 2 * wave, sB = 2 * wave + 1;  // this wave's c/h sequences
    float cA = 0.0f, cB = 0.0f;

    __syncthreads();   // ibuf + hbuf visible

    // prefetch EW rows for t=0 (wave-uniform char index, per-lane column)
    float ew[S_SEQ];
#pragma unroll
    for (int s = 0; s < S_SEQ; ++s)
        ew[s] = EWb[ibuf[s * TC_LEN] * G4_N + j];

    for (int t = 0; t < TC_LEN; ++t) {
        // ---- acc[s] = ew[s] (x-proj + bias, precomputed) ----
        float acc[S_SEQ];
#pragma unroll
        for (int s = 0; s < S_SEQ; ++s) acc[s] = ew[s];

        // ---- prefetch next timestep's EW rows (hidden under matmul) ----
        if (t + 1 < TC_LEN) {
#pragma unroll
            for (int s = 0; s < S_SEQ; ++s)
                ew[s] = EWb[ibuf[s * TC_LEN + t + 1] * G4_N + j];
        }

        // ---- acc[s] += h[s] . U[:,j]  (h broadcast from LDS) ----
#pragma unroll
        for (int k4 = 0; k4 < H_N / 4; ++k4) {
#pragma unroll
            for (int s = 0; s < S_SEQ; ++s) {
                const float4 hv = *reinterpret_cast<const float4*>(&hbuf[s][k4 * 4]);
                acc[s] = fmaf(hv.x, Ureg[4 * k4 + 0], acc[s]);
                acc[s] = fmaf(hv.y, Ureg[4 * k4 + 1], acc[s]);
                acc[s] = fmaf(hv.z, Ureg[4 * k4 + 2], acc[s]);
                acc[s] = fmaf(hv.w, Ureg[4 * k4 + 3], acc[s]);
            }
        }

        // ---- nonlinearity (wave-uniform branch) + gate exchange ----
#pragma unroll
        for (int s = 0; s < S_SEQ; ++s) {
            const float z = acc[s];
            abuf[s][j] = (wave == 2) ? tanh_f(z) : sigmoid_f(z);
        }
        __syncthreads();   // abuf visible; all z-loop hbuf reads complete

        // ---- c/h update: wave w owns sequences 2w, 2w+1 ----
        {
            const float iA = abuf[sA][u];
            const float fA = abuf[sA][u + 64];
            const float gA = abuf[sA][u + 128];
            const float oA = abuf[sA][u + 192];
            cA = fmaf(fA, cA, iA * gA);
            hbuf[sA][u] = oA * tanh_f(cA);

            const float iB = abuf[sB][u];
            const float fB = abuf[sB][u + 64];
            const float gB = abuf[sB][u + 128];
            const float oB = abuf[sB][u + 192];
            cB = fmaf(fB, cB, iB * gB);
            hbuf[sB][u] = oB * tanh_f(cB);
        }
        __syncthreads();   // hbuf(t+1) visible before next z-loop / final write
    }

    // ---- write h_last: out[(seq0+s)*64 + u], coalesced ----
#pragma unroll
    for (int rep = 0; rep < 2; ++rep) {
        const int s = wave + rep * 4;
        out[(seq0 + s) * H_N + u] = hbuf[s][u];
    }
}

extern "C" void kernel_launch(void* const* d_in, const int* in_sizes, int n_in,
                              void* d_out, int out_size, void* d_ws, size_t ws_size,
                              hipStream_t stream) {
    const int*   chars = (const int*)d_in[0];
    const float* E     = (const float*)d_in[1];
    const float* W     = (const float*)d_in[2];
    const float* U     = (const float*)d_in[3];
    const float* b     = (const float*)d_in[4];
    float* out = (float*)d_out;
    float* EWb = (float*)d_ws;                    // 128*256*4 = 131072 B

    const int N = in_sizes[0] / TC_LEN;           // 32768 sequences
    const int blocks = (N + S_SEQ - 1) / S_SEQ;   // 4096

    ew_precompute<<<V_N, G4_N, 0, stream>>>(E, W, b, EWb);
    char_lstm_kernel<<<blocks, G4_N, 0, stream>>>(chars, U, EWb, out);
}

// Round 3
// 2053.622 us; speedup vs baseline: 13.5424x; 5.8261x over previous
//
#include <hip/hip_runtime.h>
#include <hip/hip_bf16.h>

// CharLSTM: B=128, TW=256, TC=25, V=128, D=32, H=64 (4H=256)
// N = 32768 independent length-25 sequences.
//
// R3 design (R2 + spill fix):
//  - Prologue kernel computes EWb[v][j] = (E.W)[v][j] + b[j] (131 KB, L2).
//  - Main kernel: 256 threads = gate-column j; block owns 8 sequences.
//    Thread regs: Ureg[64] + acc[8] + c[2]  (~74 named; ew[] eliminated —
//    next-step EWb rows prefetch directly into the dead acc registers).
//  - __launch_bounds__(256,1): allow up to 512 VGPR so the allocator
//    does NOT spill to meet a 4-wave occupancy target (R1/R2 failure:
//    VGPR pinned at 128, ~40 GB/dispatch of scratch traffic).

#define S_SEQ 8
#define TC_LEN 25
#define H_N 64
#define D_N 32
#define G4_N 256
#define V_N 128

__device__ __forceinline__ float sigmoid_f(float x) {
    return __fdividef(1.0f, 1.0f + __expf(-x));
}
__device__ __forceinline__ float tanh_f(float x) {
    // tanh(x) = 1 - 2/(exp(2x)+1); exact at saturation, ~1e-7 rel error.
    return 1.0f - __fdividef(2.0f, __expf(2.0f * x) + 1.0f);
}

// ---- prologue: EWb = E*W + b  (128 vocab rows x 256 gate cols) ----
__global__ void ew_precompute(const float* __restrict__ E,
                              const float* __restrict__ W,
                              const float* __restrict__ b,
                              float* __restrict__ EWb) {
    const int v = blockIdx.x;    // vocab row
    const int j = threadIdx.x;   // gate column
    float acc = b[j];
#pragma unroll
    for (int d = 0; d < D_N; ++d)
        acc = fmaf(E[v * D_N + d], W[d * G4_N + j], acc);
    EWb[v * G4_N + j] = acc;
}

__global__ __launch_bounds__(256, 1) void char_lstm_kernel(
    const int* __restrict__ chars,   // [N][25]
    const float* __restrict__ U,     // [64][256]
    const float* __restrict__ EWb,   // [128][256]
    float* __restrict__ out)         // [N][64]
{
    const int j = threadIdx.x;            // gate column 0..255
    const int seq0 = blockIdx.x * S_SEQ;

    __shared__ __align__(16) float hbuf[S_SEQ][H_N];     // 2 KB
    __shared__ __align__(16) float abuf[S_SEQ][G4_N];    // 8 KB
    __shared__ int ibuf[S_SEQ * TC_LEN];                 // 800 B

    // U column j into registers (coalesced, L2-hot: 64 KB table)
    float Ureg[H_N];
#pragma unroll
    for (int k = 0; k < H_N; ++k) Ureg[k] = U[k * G4_N + j];

    // stage this block's chars (200 consecutive ints, coalesced)
    if (j < S_SEQ * TC_LEN) ibuf[j] = chars[seq0 * TC_LEN + j];

    // zero initial h
    for (int r = j; r < S_SEQ * H_N; r += 256) (&hbuf[0][0])[r] = 0.0f;

    const int wave = j >> 6;                 // 0..3 == gate (i,f,g,o), wave-uniform
    const int u = j & 63;                    // unit index
    const int sA = 2 * wave, sB = 2 * wave + 1;  // this wave's c/h sequences
    float cA = 0.0f, cB = 0.0f;

    __syncthreads();   // ibuf + hbuf visible

    // acc starts as the precomputed x-projection (EW row for t=0)
    float acc[S_SEQ];
#pragma unroll
    for (int s = 0; s < S_SEQ; ++s)
        acc[s] = EWb[ibuf[s * TC_LEN] * G4_N + j];

    for (int t = 0; t < TC_LEN; ++t) {
        // ---- acc[s] += h[s] . U[:,j]  (h broadcast from LDS) ----
#pragma unroll
        for (int k4 = 0; k4 < H_N / 4; ++k4) {
#pragma unroll
            for (int s = 0; s < S_SEQ; ++s) {
                const float4 hv = *reinterpret_cast<const float4*>(&hbuf[s][k4 * 4]);
                acc[s] = fmaf(hv.x, Ureg[4 * k4 + 0], acc[s]);
                acc[s] = fmaf(hv.y, Ureg[4 * k4 + 1], acc[s]);
                acc[s] = fmaf(hv.z, Ureg[4 * k4 + 2], acc[s]);
                acc[s] = fmaf(hv.w, Ureg[4 * k4 + 3], acc[s]);
            }
        }

        // ---- nonlinearity (wave-uniform branch) + gate exchange ----
#pragma unroll
        for (int s = 0; s < S_SEQ; ++s) {
            const float z = acc[s];
            abuf[s][j] = (wave == 2) ? tanh_f(z) : sigmoid_f(z);
        }

        // ---- prefetch next timestep's EW rows into (now dead) acc ----
        if (t + 1 < TC_LEN) {
#pragma unroll
            for (int s = 0; s < S_SEQ; ++s)
                acc[s] = EWb[ibuf[s * TC_LEN + t + 1] * G4_N + j];
        }

        __syncthreads();   // abuf visible; all z-loop hbuf reads complete

        // ---- c/h update: wave w owns sequences 2w, 2w+1 ----
        {
            const float iA = abuf[sA][u];
            const float fA = abuf[sA][u + 64];
            const float gA = abuf[sA][u + 128];
            const float oA = abuf[sA][u + 192];
            cA = fmaf(fA, cA, iA * gA);
            hbuf[sA][u] = oA * tanh_f(cA);

            const float iB = abuf[sB][u];
            const float fB = abuf[sB][u + 64];
            const float gB = abuf[sB][u + 128];
            const float oB = abuf[sB][u + 192];
            cB = fmaf(fB, cB, iB * gB);
            hbuf[sB][u] = oB * tanh_f(cB);
        }
        __syncthreads();   // hbuf(t+1) visible before next z-loop / final write
    }

    // ---- write h_last: out[(seq0+s)*64 + u], coalesced ----
#pragma unroll
    for (int rep = 0; rep < 2; ++rep) {
        const int s = wave + rep * 4;
        out[(seq0 + s) * H_N + u] = hbuf[s][u];
    }
}

extern "C" void kernel_launch(void* const* d_in, const int* in_sizes, int n_in,
                              void* d_out, int out_size, void* d_ws, size_t ws_size,
                              hipStream_t stream) {
    const int*   chars = (const int*)d_in[0];
    const float* E     = (const float*)d_in[1];
    const float* W     = (const float*)d_in[2];
    const float* U     = (const float*)d_in[3];
    const float* b     = (const float*)d_in[4];
    float* out = (float*)d_out;
    float* EWb = (float*)d_ws;                    // 128*256*4 = 131072 B

    const int N = in_sizes[0] / TC_LEN;           // 32768 sequences
    const int blocks = (N + S_SEQ - 1) / S_SEQ;   // 4096

    ew_precompute<<<V_N, G4_N, 0, stream>>>(E, W, b, EWb);
    char_lstm_kernel<<<blocks, G4_N, 0, stream>>>(chars, U, EWb, out);
}

// Round 4
// 191.341 us; speedup vs baseline: 145.3480x; 10.7328x over previous
//
#include <hip/hip_runtime.h>
#include <hip/hip_bf16.h>

// CharLSTM: B=128, TW=256, TC=25, V=128, D=32, H=64 (4H=256), N=32768 seqs.
//
// R4: MFMA formulation.
//  - Prologue: EWb[v][j] = (E.W)[v][j] + b[j]  (128x256 f32, L2-resident).
//  - Main: block = 16 sequences, 256 threads (4 waves).
//    Per timestep: z[16x256] = EWrow + h[16x64] . U[64x256] via
//    mfma_f32_16x16x32_bf16 with hi/lo bf16 split (3 terms) for fp32-class
//    precision. Wave w owns n-tiles {w,4+w,8+w,12+w} = one 16-col tile per
//    gate -> i,f,g,o for the same (seq,unit) land in the SAME lane/reg ->
//    lane-local activations + c/h update (c never leaves registers).
//  - h (hi/lo bf16) double-buffered in LDS [16][64], XOR-swizzled
//    (byte ^= (row&7)<<4) to break the 128B-stride bank pattern.
//    One barrier per timestep.
//  - k-mapping for A/B fragments: k = ks*32 + 8*(lane>>4) + e on BOTH
//    operands -> result invariant to the HW's true per-lane k order.

#define SEQ_M 16
#define TC_LEN 25
#define H_N 64
#define D_N 32
#define G4_N 256
#define V_N 128

typedef __attribute__((ext_vector_type(8))) short bf16x8;
typedef __attribute__((ext_vector_type(4))) float f32x4;

__device__ __forceinline__ float sigmoid_f(float x) {
    return __fdividef(1.0f, 1.0f + __expf(-x));
}
__device__ __forceinline__ float tanh_f(float x) {
    return 1.0f - __fdividef(2.0f, __expf(2.0f * x) + 1.0f);
}
__device__ __forceinline__ ushort bf16_rne(float x) {
    const uint u = __float_as_uint(x);
    return (ushort)((u + 0x7fffu + ((u >> 16) & 1u)) >> 16);
}
__device__ __forceinline__ float bf16_tof(ushort h) {
    return __uint_as_float(((uint)h) << 16);
}
// swizzled byte offset into a [16][64] bf16 (2 KB) tile
__device__ __forceinline__ int hswz(int row, int kbyte) {
    const int b = row * 128 + kbyte;
    return b ^ ((row & 7) << 4);
}

// ---- prologue: EWb = E*W + b ----
__global__ void ew_precompute(const float* __restrict__ E,
                              const float* __restrict__ W,
                              const float* __restrict__ b,
                              float* __restrict__ EWb) {
    const int v = blockIdx.x;
    const int j = threadIdx.x;
    float acc = b[j];
#pragma unroll
    for (int d = 0; d < D_N; ++d)
        acc = fmaf(E[v * D_N + d], W[d * G4_N + j], acc);
    EWb[v * G4_N + j] = acc;
}

__global__ __launch_bounds__(256, 1) void char_lstm_mfma(
    const int* __restrict__ chars,   // [N][25]
    const float* __restrict__ U,     // [64][256]
    const float* __restrict__ EWb,   // [128][256]
    float* __restrict__ out)         // [N][64]
{
    const int j = threadIdx.x;
    const int w = j >> 6;            // wave 0..3
    const int l = j & 63;            // lane
    const int q = l >> 4;            // lane group 0..3
    const int n16 = l & 15;          // 0..15
    const int seq0 = blockIdx.x * SEQ_M;

    __shared__ int ibuf[SEQ_M * TC_LEN];             // 1.6 KB
    __shared__ ushort hbuf[2][2][SEQ_M * H_N];       // [buf][hi/lo], 8 KB

    // stage chars (400 consecutive ints)
    for (int idx = j; idx < SEQ_M * TC_LEN; idx += 256)
        ibuf[idx] = chars[seq0 * TC_LEN + idx];
    // zero h buffer 0 (hi+lo = 2048 ushorts = 1024 uints)
    {
        uint* z = (uint*)&hbuf[0][0][0];
        for (int idx = j; idx < 1024; idx += 256) z[idx] = 0u;
    }

    // ---- preload U fragments (hi/lo), own k-map: k = ks*32 + 8q + e ----
    bf16x8 bh[4][2], bl[4][2];
#pragma unroll
    for (int tile = 0; tile < 4; ++tile) {
        const int colg = tile * 64 + w * 16 + n16;
#pragma unroll
        for (int ks = 0; ks < 2; ++ks) {
#pragma unroll
            for (int e = 0; e < 8; ++e) {
                const int k = ks * 32 + 8 * q + e;
                const float uv = U[k * G4_N + colg];
                const ushort hi = bf16_rne(uv);
                bh[tile][ks][e] = (short)hi;
                bl[tile][ks][e] = (short)bf16_rne(uv - bf16_tof(hi));
            }
        }
    }

    __syncthreads();

    // ---- EW rows for t=0 ----
    float ew[4][4];   // [r][tile]
#pragma unroll
    for (int r = 0; r < 4; ++r) {
        const int ch = ibuf[(4 * q + r) * TC_LEN + 0];
#pragma unroll
        for (int tile = 0; tile < 4; ++tile)
            ew[r][tile] = EWb[ch * G4_N + tile * 64 + w * 16 + n16];
    }

    float c[4] = {0.0f, 0.0f, 0.0f, 0.0f};
    float hfin[4];
    const int u = w * 16 + n16;
    int cur = 0;

    for (int t = 0; t < TC_LEN; ++t) {
        // acc init: z = EWb row (x-proj + bias); reg r <-> seq row 4q+r
        f32x4 acc[4];
#pragma unroll
        for (int tile = 0; tile < 4; ++tile) {
            acc[tile][0] = ew[0][tile];
            acc[tile][1] = ew[1][tile];
            acc[tile][2] = ew[2][tile];
            acc[tile][3] = ew[3][tile];
        }

        // A fragments: lane = row n16, k = ks*32 + 8q + e (16B contiguous)
        const char* hb_hi = (const char*)&hbuf[cur][0][0];
        const char* hb_lo = (const char*)&hbuf[cur][1][0];
        bf16x8 ah[2], al[2];
#pragma unroll
        for (int ks = 0; ks < 2; ++ks) {
            const int off = hswz(n16, ks * 64 + 16 * q);
            ah[ks] = *(const bf16x8*)(hb_hi + off);
            al[ks] = *(const bf16x8*)(hb_lo + off);
        }

        // prefetch next timestep's EW rows (hidden under MFMA)
        if (t + 1 < TC_LEN) {
#pragma unroll
            for (int r = 0; r < 4; ++r) {
                const int ch = ibuf[(4 * q + r) * TC_LEN + t + 1];
#pragma unroll
                for (int tile = 0; tile < 4; ++tile)
                    ew[r][tile] = EWb[ch * G4_N + tile * 64 + w * 16 + n16];
            }
        }

        // z += h.U : 3-term hi/lo split, 24 MFMA
#pragma unroll
        for (int tile = 0; tile < 4; ++tile) {
#pragma unroll
            for (int ks = 0; ks < 2; ++ks) {
                acc[tile] = __builtin_amdgcn_mfma_f32_16x16x32_bf16(
                    ah[ks], bh[tile][ks], acc[tile], 0, 0, 0);
                acc[tile] = __builtin_amdgcn_mfma_f32_16x16x32_bf16(
                    ah[ks], bl[tile][ks], acc[tile], 0, 0, 0);
                acc[tile] = __builtin_amdgcn_mfma_f32_16x16x32_bf16(
                    al[ks], bh[tile][ks], acc[tile], 0, 0, 0);
            }
        }

        // activations + cell update (lane-local; tile 0..3 = i,f,g,o)
        char* hn_hi = (char*)&hbuf[cur ^ 1][0][0];
        char* hn_lo = (char*)&hbuf[cur ^ 1][1][0];
#pragma unroll
        for (int r = 0; r < 4; ++r) {
            const float iv = sigmoid_f(acc[0][r]);
            const float fv = sigmoid_f(acc[1][r]);
            const float gv = tanh_f(acc[2][r]);
            const float ov = sigmoid_f(acc[3][r]);
            c[r] = fmaf(fv, c[r], iv * gv);
            const float hv = ov * tanh_f(c[r]);
            hfin[r] = hv;
            const ushort hi = bf16_rne(hv);
            const ushort lo = bf16_rne(hv - bf16_tof(hi));
            const int off = hswz(4 * q + r, u * 2);
            *(ushort*)(hn_hi + off) = hi;
            *(ushort*)(hn_lo + off) = lo;
        }
        __syncthreads();
        cur ^= 1;
    }

    // ---- write h_last ----
#pragma unroll
    for (int r = 0; r < 4; ++r)
        out[(seq0 + 4 * q + r) * H_N + u] = hfin[r];
}

extern "C" void kernel_launch(void* const* d_in, const int* in_sizes, int n_in,
                              void* d_out, int out_size, void* d_ws, size_t ws_size,
                              hipStream_t stream) {
    const int*   chars = (const int*)d_in[0];
    const float* E     = (const float*)d_in[1];
    const float* W     = (const float*)d_in[2];
    const float* U     = (const float*)d_in[3];
    const float* b     = (const float*)d_in[4];
    float* out = (float*)d_out;
    float* EWb = (float*)d_ws;                      // 131072 B

    const int N = in_sizes[0] / TC_LEN;             // 32768
    const int blocks = N / SEQ_M;                   // 2048

    ew_precompute<<<V_N, G4_N, 0, stream>>>(E, W, b, EWb);
    char_lstm_mfma<<<blocks, 256, 0, stream>>>(chars, U, EWb, out);
}

// Round 5
// 114.049 us; speedup vs baseline: 243.8515x; 1.6777x over previous
//
#include <hip/hip_runtime.h>
#include <hip/hip_bf16.h>

// CharLSTM: B=128, TW=256, TC=25, V=128, D=32, H=64 (4H=256), N=32768 seqs.
//
// R5 = R4 (MFMA, hi/lo bf16 split, lane-local gates) + VALU-pipe diet:
//  - EWr[v][col16][tile]: permuted + PRE-SCALED x-projection table.
//    Scale -log2(e) on sigmoid gate cols, +2log2(e) on g cols, folded into
//    EWr AND U -> MFMA output is directly the v_exp_f32 (exp2) argument.
//  - Common-denominator activations: i*g and o*tanh share one rcp each:
//    5 exp + 3 rcp per unit (was 5+5). Raw exp2/rcp builtins.
//  - Truncation-based hi/lo split of h (4 ops/value vs ~12 for rne).
//  - chars transposed in LDS -> 1 ds_read_b128 fetches 4 char indices;
//    EWr float4 loads (4 per thread/timestep, was 16 scalar).

#define SEQ_M 16
#define TC_LEN 25
#define H_N 64
#define D_N 32
#define G4_N 256
#define V_N 128

typedef __attribute__((ext_vector_type(8))) short bf16x8;
typedef __attribute__((ext_vector_type(4))) float f32x4;
typedef __attribute__((ext_vector_type(4))) int i32x4;

#define SCALE_SIG (-1.4426950408889634f)   /* -log2(e)  */
#define SCALE_G   ( 2.8853900817779268f)   /* 2*log2(e) */

__device__ __forceinline__ ushort bf16_rne(float x) {
    const uint u = __float_as_uint(x);
    return (ushort)((u + 0x7fffu + ((u >> 16) & 1u)) >> 16);
}
__device__ __forceinline__ float bf16_tof(ushort h) {
    return __uint_as_float(((uint)h) << 16);
}
// swizzled byte offset into a [16][64] bf16 (2 KB) tile
__device__ __forceinline__ int hswz(int row, int kbyte) {
    const int b = row * 128 + kbyte;
    return b ^ ((row & 7) << 4);
}

// ---- prologue: EWr[v][c16][tile] = ((E.W)[v][tile*64+c16] + b) * gate_scale ----
__global__ void ew_precompute(const float* __restrict__ E,
                              const float* __restrict__ W,
                              const float* __restrict__ b,
                              float* __restrict__ EWr) {
    const int v = blockIdx.x;
    const int j = threadIdx.x;           // output col = (j>>6)*64 + (j&63)
    float acc = b[j];
#pragma unroll
    for (int d = 0; d < D_N; ++d)
        acc = fmaf(E[v * D_N + d], W[d * G4_N + j], acc);
    const int tile = j >> 6, c16 = j & 63;
    const float scale = (tile == 2) ? SCALE_G : SCALE_SIG;
    EWr[v * G4_N + c16 * 4 + tile] = acc * scale;
}

__global__ __launch_bounds__(256, 1) void char_lstm_mfma(
    const int* __restrict__ chars,   // [N][25]
    const float* __restrict__ U,     // [64][256]
    const float* __restrict__ EWr,   // [128][64][4] permuted+scaled
    float* __restrict__ out)         // [N][64]
{
    const int j = threadIdx.x;
    const int w = j >> 6;            // wave 0..3
    const int l = j & 63;            // lane
    const int q = l >> 4;            // lane group 0..3
    const int n16 = l & 15;          // 0..15
    const int c16 = w * 16 + n16;    // this thread's unit/col-in-gate
    const int seq0 = blockIdx.x * SEQ_M;

    __shared__ int ibuf[TC_LEN][SEQ_M];              // transposed chars, 1.6 KB
    __shared__ ushort hbuf[2][2][SEQ_M * H_N];       // [buf][hi/lo], 8 KB

    // stage chars transposed: ibuf[t][s]
    for (int idx = j; idx < TC_LEN * SEQ_M; idx += 256) {
        const int s = idx & 15, tt = idx >> 4;
        ibuf[tt][s] = chars[(seq0 + s) * TC_LEN + tt];
    }
    // zero h buffer 0 (hi+lo planes)
    {
        uint* z = (uint*)&hbuf[0][0][0];
        for (int idx = j; idx < 1024; idx += 256) z[idx] = 0u;
    }

    // ---- preload U fragments (pre-scaled, hi/lo), k-map k = ks*32+8q+e ----
    bf16x8 bh[4][2], bl[4][2];
#pragma unroll
    for (int tile = 0; tile < 4; ++tile) {
        const int colg = tile * 64 + c16;
        const float scale = (tile == 2) ? SCALE_G : SCALE_SIG;
#pragma unroll
        for (int ks = 0; ks < 2; ++ks) {
#pragma unroll
            for (int e = 0; e < 8; ++e) {
                const int k = ks * 32 + 8 * q + e;
                const float uv = U[k * G4_N + colg] * scale;
                const ushort hi = bf16_rne(uv);
                bh[tile][ks][e] = (short)hi;
                bl[tile][ks][e] = (short)bf16_rne(uv - bf16_tof(hi));
            }
        }
    }

    __syncthreads();

    // hoisted LDS offsets
    const int offA0 = hswz(n16, 16 * q);
    const int offA1 = hswz(n16, 64 + 16 * q);
    int offW[4];
#pragma unroll
    for (int r = 0; r < 4; ++r) offW[r] = hswz(4 * q + r, c16 * 2);

    // ---- EWr rows for t=0: one b128 char read + 4 float4 loads ----
    f32x4 ewv[4];
    {
        const i32x4 cv = *(const i32x4*)&ibuf[0][4 * q];
#pragma unroll
        for (int r = 0; r < 4; ++r)
            ewv[r] = *(const f32x4*)(EWr + cv[r] * G4_N + c16 * 4);
    }

    float c[4] = {0.0f, 0.0f, 0.0f, 0.0f};
    float hfin[4];
    int cur = 0;

    for (int t = 0; t < TC_LEN; ++t) {
        // acc init: acc[tile][r] = ewv[r][tile]  (scaled z from x-proj)
        f32x4 acc[4];
#pragma unroll
        for (int tile = 0; tile < 4; ++tile) {
            acc[tile][0] = ewv[0][tile];
            acc[tile][1] = ewv[1][tile];
            acc[tile][2] = ewv[2][tile];
            acc[tile][3] = ewv[3][tile];
        }

        // A fragments (hi/lo planes of h)
        const char* hb_hi = (const char*)&hbuf[cur][0][0];
        const char* hb_lo = (const char*)&hbuf[cur][1][0];
        const bf16x8 ah0 = *(const bf16x8*)(hb_hi + offA0);
        const bf16x8 ah1 = *(const bf16x8*)(hb_hi + offA1);
        const bf16x8 al0 = *(const bf16x8*)(hb_lo + offA0);
        const bf16x8 al1 = *(const bf16x8*)(hb_lo + offA1);

        // prefetch next timestep's EWr rows (lands under MFMA + activations)
        if (t + 1 < TC_LEN) {
            const i32x4 cv = *(const i32x4*)&ibuf[t + 1][4 * q];
#pragma unroll
            for (int r = 0; r < 4; ++r)
                ewv[r] = *(const f32x4*)(EWr + cv[r] * G4_N + c16 * 4);
        }

        // z += h.U : 3-term hi/lo split, 24 MFMA
#pragma unroll
        for (int tile = 0; tile < 4; ++tile) {
            acc[tile] = __builtin_amdgcn_mfma_f32_16x16x32_bf16(ah0, bh[tile][0], acc[tile], 0, 0, 0);
            acc[tile] = __builtin_amdgcn_mfma_f32_16x16x32_bf16(ah0, bl[tile][0], acc[tile], 0, 0, 0);
            acc[tile] = __builtin_amdgcn_mfma_f32_16x16x32_bf16(al0, bh[tile][0], acc[tile], 0, 0, 0);
            acc[tile] = __builtin_amdgcn_mfma_f32_16x16x32_bf16(ah1, bh[tile][1], acc[tile], 0, 0, 0);
            acc[tile] = __builtin_amdgcn_mfma_f32_16x16x32_bf16(ah1, bl[tile][1], acc[tile], 0, 0, 0);
            acc[tile] = __builtin_amdgcn_mfma_f32_16x16x32_bf16(al1, bh[tile][1], acc[tile], 0, 0, 0);
        }

        // activations: acc is pre-scaled -> exp2 directly.
        // i*g = (e2g-1)*rcp(di*dg);  h = (e2c-1)*rcp(do*dh)
        char* hn_hi = (char*)&hbuf[cur ^ 1][0][0];
        char* hn_lo = (char*)&hbuf[cur ^ 1][1][0];
#pragma unroll
        for (int r = 0; r < 4; ++r) {
            const float di = 1.0f + __builtin_amdgcn_exp2f(acc[0][r]);
            const float df = 1.0f + __builtin_amdgcn_exp2f(acc[1][r]);
            const float e2g = __builtin_amdgcn_exp2f(acc[2][r]);
            const float do_ = 1.0f + __builtin_amdgcn_exp2f(acc[3][r]);
            const float ng = e2g - 1.0f, dg = e2g + 1.0f;
            const float pig = __builtin_amdgcn_rcpf(di * dg);
            const float pf  = __builtin_amdgcn_rcpf(df);
            c[r] = fmaf(c[r], pf, ng * pig);           // f*c + i*g
            const float e2c = __builtin_amdgcn_exp2f(c[r] * SCALE_G);
            const float nh = e2c - 1.0f, dh = e2c + 1.0f;
            const float h = nh * __builtin_amdgcn_rcpf(do_ * dh);  // o*tanh(c)
            hfin[r] = h;
            // truncation hi/lo split (err ~2^-17, invisible vs 2^-12 floor)
            const uint hu = __float_as_uint(h);
            const float hi_f = __uint_as_float(hu & 0xffff0000u);
            const float lo_f = h - hi_f;
            *(ushort*)(hn_hi + offW[r]) = (ushort)(hu >> 16);
            *(ushort*)(hn_lo + offW[r]) = (ushort)(__float_as_uint(lo_f) >> 16);
        }
        __syncthreads();
        cur ^= 1;
    }

    // ---- write h_last ----
#pragma unroll
    for (int r = 0; r < 4; ++r)
        out[(seq0 + 4 * q + r) * H_N + c16] = hfin[r];
}

extern "C" void kernel_launch(void* const* d_in, const int* in_sizes, int n_in,
                              void* d_out, int out_size, void* d_ws, size_t ws_size,
                              hipStream_t stream) {
    const int*   chars = (const int*)d_in[0];
    const float* E     = (const float*)d_in[1];
    const float* W     = (const float*)d_in[2];
    const float* U     = (const float*)d_in[3];
    const float* b     = (const float*)d_in[4];
    float* out = (float*)d_out;
    float* EWr = (float*)d_ws;                      // 131072 B

    const int N = in_sizes[0] / TC_LEN;             // 32768
    const int blocks = N / SEQ_M;                   // 2048

    ew_precompute<<<V_N, G4_N, 0, stream>>>(E, W, b, EWr);
    char_lstm_mfma<<<blocks, 256, 0, stream>>>(chars, U, EWr, out);
}